// Round 6
// baseline (528.351 us; speedup 1.0000x reference)
//
#include <hip/hip_runtime.h>

#define H 256

typedef __attribute__((ext_vector_type(8))) short short8;
typedef __attribute__((ext_vector_type(8))) unsigned short ushort8v;
typedef __attribute__((ext_vector_type(16))) float f32x16;

__device__ __forceinline__ ushort f2bf(float f) {
  unsigned u = __float_as_uint(f);
  unsigned r = (u + 0x7fffu + ((u >> 16) & 1u)) >> 16;
  return (ushort)r;
}
__device__ __forceinline__ float bf2f(ushort s) {
  return __uint_as_float(((unsigned)s) << 16);
}

// ============ frag-major layouts ============
// A-type (red, h): panel p = row>>7, r = row&127; chunk l = k>>3 (0..31).
//   byte addr = p*65536 + l*2048 + r*16   (panel = 64 KB)
// W (both mats, gidx = [ih: gate*256+col | hh: 768+gate*256+col]):
//   byte addr = l*24576 + gidx*16         (l = k>>3, 0..31; total 768 KB)

// ---------- h: f32 -> bf16 row-major (for gather) + frag-major (for GEMM) ----------
__global__ void k_cvt_h(const float* __restrict__ src, ushort* __restrict__ h16row,
                        ushort* __restrict__ hfm, int nrows) {
  int t = blockIdx.x * blockDim.x + threadIdx.x;
  if (t >= nrows * 32) return;
  const int row = t >> 5, l = t & 31;
  const float4 fa = *(const float4*)&src[(size_t)row * H + l * 8];
  const float4 fb = *(const float4*)&src[(size_t)row * H + l * 8 + 4];
  ushort8v o;
  o[0] = f2bf(fa.x); o[1] = f2bf(fa.y); o[2] = f2bf(fa.z); o[3] = f2bf(fa.w);
  o[4] = f2bf(fb.x); o[5] = f2bf(fb.y); o[6] = f2bf(fb.z); o[7] = f2bf(fb.w);
  *(ushort8v*)&h16row[(size_t)row * H + l * 8] = o;
  const int p = row >> 7, r = row & 127;
  *(ushort8v*)((char*)hfm + (size_t)p * 65536 + (size_t)l * 2048 + r * 16) = o;
}

// ---------- W: f32 -> bf16 frag-major ----------
__global__ void k_cvt_w(const float* __restrict__ w, ushort* __restrict__ wfm, int gbase) {
  int t = blockIdx.x * blockDim.x + threadIdx.x;
  if (t >= 768 * 32) return;
  const int j = t >> 5, l = t & 31;
  const float4 fa = *(const float4*)&w[(size_t)j * H + l * 8];
  const float4 fb = *(const float4*)&w[(size_t)j * H + l * 8 + 4];
  ushort8v o;
  o[0] = f2bf(fa.x); o[1] = f2bf(fa.y); o[2] = f2bf(fa.z); o[3] = f2bf(fa.w);
  o[4] = f2bf(fb.x); o[5] = f2bf(fb.y); o[6] = f2bf(fb.z); o[7] = f2bf(fb.w);
  *(ushort8v*)((char*)wfm + ((size_t)l * 1536 + gbase + j) * 16) = o;
}

// ---------- CSR build ----------
__global__ void k_zero(int* cnt, int n) {
  int i = blockIdx.x * blockDim.x + threadIdx.x;
  if (i < n) cnt[i] = 0;
}

// per-(dst,rel) histogram: cnt16[dst*16+rel]
__global__ void k_hist(const int* __restrict__ dst, const int* __restrict__ rel,
                       int* __restrict__ cnt16, int ne) {
  int e = blockIdx.x * blockDim.x + threadIdx.x;
  if (e < ne) atomicAdd(&cnt16[dst[e] * 16 + rel[e]], 1);
}

__device__ __forceinline__ int node_cnt(const int* __restrict__ cnt16, int i) {
  int s = 0;
#pragma unroll
  for (int r = 0; r < 16; ++r) s += cnt16[i * 16 + r];
  return s;
}

__global__ __launch_bounds__(256) void k_scan1(const int* __restrict__ cnt16,
                                               int* __restrict__ bsum, int n) {
  __shared__ int s[256];
  int t = threadIdx.x, i = blockIdx.x * 256 + t;
  int v = (i < n) ? node_cnt(cnt16, i) : 0;
  s[t] = v;
  __syncthreads();
  for (int o = 128; o > 0; o >>= 1) {
    if (t < o) s[t] += s[t + o];
    __syncthreads();
  }
  if (t == 0) bsum[blockIdx.x] = s[0];
}

__global__ __launch_bounds__(256) void k_scan2(const int* __restrict__ bsum,
                                               int* __restrict__ bpre, int nb,
                                               int* __restrict__ offs, int n) {
  __shared__ int s[256];
  int t = threadIdx.x;
  int v = (t < nb) ? bsum[t] : 0;
  s[t] = v;
  __syncthreads();
  for (int o = 1; o < 256; o <<= 1) {
    int x = (t >= o) ? s[t - o] : 0;
    __syncthreads();
    s[t] += x;
    __syncthreads();
  }
  if (t < nb) bpre[t] = s[t] - v;
  if (t == 255) offs[n] = s[255];
}

__global__ __launch_bounds__(256) void k_scan3(const int* __restrict__ cnt16,
                                               const int* __restrict__ bpre,
                                               int* __restrict__ offs,
                                               int* __restrict__ cursor, int n) {
  __shared__ int s[256];
  int t = threadIdx.x, i = blockIdx.x * 256 + t;
  int v = (i < n) ? node_cnt(cnt16, i) : 0;
  s[t] = v;
  __syncthreads();
  for (int o = 1; o < 256; o <<= 1) {
    int x = (t >= o) ? s[t - o] : 0;
    __syncthreads();
    s[t] += x;
    __syncthreads();
  }
  if (i < n) {
    int e = bpre[blockIdx.x] + s[t] - v;
    offs[i] = e;
    cursor[i] = e;
  }
}

__global__ void k_fill(const int* __restrict__ src, const int* __restrict__ dst,
                       int* __restrict__ cursor, int* __restrict__ bucket, int ne) {
  int e = blockIdx.x * blockDim.x + threadIdx.x;
  if (e < ne) {
    int p = atomicAdd(&cursor[dst[e]], 1);
    bucket[p] = src[e];
  }
}

// ---------- gather-reduce: half-wave per node; edge loop = h only; relv via counts ----------
__global__ __launch_bounds__(256) void k_gather(const ushort* __restrict__ h16,
                                                const float* __restrict__ relv,
                                                const int* __restrict__ offs,
                                                const int* __restrict__ bucket,
                                                const int* __restrict__ cnt16,
                                                ushort* __restrict__ redfm, int nn) {
  const int hw = threadIdx.x >> 5;
  const int l = threadIdx.x & 31;
  const int node = blockIdx.x * 8 + hw;
  if (node >= nn) return;
  const int beg = offs[node], end = offs[node + 1];
  float acc[8] = {0.f, 0.f, 0.f, 0.f, 0.f, 0.f, 0.f, 0.f};
  int i = beg;
  for (; i + 4 <= end; i += 4) {
    const int s0 = bucket[i], s1 = bucket[i + 1], s2 = bucket[i + 2], s3 = bucket[i + 3];
    const ushort8v a0 = *(const ushort8v*)&h16[(size_t)s0 * H + l * 8];
    const ushort8v a1 = *(const ushort8v*)&h16[(size_t)s1 * H + l * 8];
    const ushort8v a2 = *(const ushort8v*)&h16[(size_t)s2 * H + l * 8];
    const ushort8v a3 = *(const ushort8v*)&h16[(size_t)s3 * H + l * 8];
#pragma unroll
    for (int e = 0; e < 8; ++e)
      acc[e] += (bf2f(a0[e]) + bf2f(a1[e])) + (bf2f(a2[e]) + bf2f(a3[e]));
  }
  for (; i < end; ++i) {
    const int s0 = bucket[i];
    const ushort8v a0 = *(const ushort8v*)&h16[(size_t)s0 * H + l * 8];
#pragma unroll
    for (int e = 0; e < 8; ++e) acc[e] += bf2f(a0[e]);
  }
  // add relation vectors weighted by per-rel counts (relv is L1/L2-resident)
#pragma unroll 4
  for (int r = 0; r < 16; ++r) {
    const float cf = (float)cnt16[node * 16 + r];
    const float4 ra = *(const float4*)&relv[r * H + l * 8];
    const float4 rb = *(const float4*)&relv[r * H + l * 8 + 4];
    acc[0] += cf * ra.x; acc[1] += cf * ra.y; acc[2] += cf * ra.z; acc[3] += cf * ra.w;
    acc[4] += cf * rb.x; acc[5] += cf * rb.y; acc[6] += cf * rb.z; acc[7] += cf * rb.w;
  }
  ushort8v o;
#pragma unroll
  for (int e = 0; e < 8; ++e) o[e] = f2bf(acc[e]);
  const int p = node >> 7, r = node & 127;
  *(ushort8v*)((char*)redfm + (size_t)p * 65536 + (size_t)l * 2048 + r * 16) = o;
}

// ---------- fused dual-GEMM (32x32x16 bf16 MFMA, register-direct) + GRU ----------
// Grid (782): block = 256 thr (4 waves) x 64 rows; col-windows cw=0..3 looped inside.
// Waves: wid0 ih C=0, wid1 ih C=32, wid2 hh C=0, wid3 hh C=32. Per wave per cw:
// 2 row-tiles x 3 gates = 6 acc tiles (96 AGPR). No LDS/barriers in K-loop.
// 3 blocks/CU (12 waves) by 168-reg budget. Epilogue h read from bf16 hfm (L2-hot).
__global__ __launch_bounds__(256, 3) void k_gru_mfma(
    const ushort* __restrict__ redfm, const ushort* __restrict__ hfm,
    const ushort* __restrict__ wfm,
    const float* __restrict__ b_ih, const float* __restrict__ b_hh,
    float* __restrict__ out, int nn) {
  __shared__ unsigned char smem[24576];
  const int tid = threadIdx.x;
  const int wid = tid >> 6;
  const int lane = tid & 63;
  const int l31 = lane & 31;
  const int lhi = lane >> 5;
  const bool is_hh = (wid >= 2);
  const int C = (wid & 1) * 32;
  const int row0 = blockIdx.x * 64;
  const int p = blockIdx.x >> 1;
  const int rbase = (blockIdx.x & 1) * 64;

  const char* amat = (const char*)(is_hh ? hfm : redfm);
  const char* wb = (const char*)wfm;
  const char* hchar = (const char*)hfm;
  const int a_base = p * 65536 + lhi * 2048 + (rbase + l31) * 16;
  const int gsel = is_hh ? 768 : 0;

  for (int cw = 0; cw < 4; ++cw) {
    const int hcol0 = cw * 64;
    const int b_base = lhi * 24576 + (gsel + hcol0 + C + l31) * 16;
    f32x16 acc[2][3] = {};
#pragma unroll
    for (int kb = 0; kb < 8; ++kb) {
#pragma unroll
      for (int kg = 0; kg < 2; ++kg) {
        const int ao = a_base + kb * 8192 + kg * 4096;
        const int bo = b_base + (kb * 4 + kg * 2) * 24576;
        const short8 a0 = *(const short8*)(amat + ao);
        const short8 a1 = *(const short8*)(amat + ao + 512);
        const short8 b0 = *(const short8*)(wb + bo);
        const short8 b1 = *(const short8*)(wb + bo + 4096);
        const short8 b2 = *(const short8*)(wb + bo + 8192);
        acc[0][0] = __builtin_amdgcn_mfma_f32_32x32x16_bf16(a0, b0, acc[0][0], 0, 0, 0);
        acc[0][1] = __builtin_amdgcn_mfma_f32_32x32x16_bf16(a0, b1, acc[0][1], 0, 0, 0);
        acc[0][2] = __builtin_amdgcn_mfma_f32_32x32x16_bf16(a0, b2, acc[0][2], 0, 0, 0);
        acc[1][0] = __builtin_amdgcn_mfma_f32_32x32x16_bf16(a1, b0, acc[1][0], 0, 0, 0);
        acc[1][1] = __builtin_amdgcn_mfma_f32_32x32x16_bf16(a1, b1, acc[1][1], 0, 0, 0);
        acc[1][2] = __builtin_amdgcn_mfma_f32_32x32x16_bf16(a1, b2, acc[1][2], 0, 0, 0);
      }
    }

    // hh waves stash gh (bf16) into LDS
    if (is_hh) {
      const int ww = wid - 2;
#pragma unroll
      for (int rt = 0; rt < 2; ++rt)
#pragma unroll
        for (int s = 0; s < 3; ++s) {
          ushort tmp[16];
#pragma unroll
          for (int r = 0; r < 16; ++r) tmp[r] = f2bf(acc[rt][s][r]);
          const int so = ww * 12288 + (rt * 3 + s) * 2048 + lane * 32;
          *(ushort8v*)&smem[so] = *(const ushort8v*)&tmp[0];
          *(ushort8v*)&smem[so + 16] = *(const ushort8v*)&tmp[8];
        }
    }
    __syncthreads();

    // ih waves: fused GRU epilogue (h read from bf16 hfm)
    if (!is_hh) {
      const int hcol = hcol0 + C + l31;
      const float bir = b_ih[hcol], biz = b_ih[256 + hcol], bin = b_ih[512 + hcol];
      const float bhr = b_hh[hcol], bhz = b_hh[256 + hcol], bhn = b_hh[512 + hcol];
      const int hv_base = p * 65536 + (hcol >> 3) * 2048 + (hcol & 7) * 2;
#pragma unroll
      for (int rt = 0; rt < 2; ++rt) {
        ushort hr_[16], hz_[16], hn_[16];
        const int so = wid * 12288 + rt * 3 * 2048 + lane * 32;
        *(ushort8v*)&hr_[0] = *(const ushort8v*)&smem[so];
        *(ushort8v*)&hr_[8] = *(const ushort8v*)&smem[so + 16];
        *(ushort8v*)&hz_[0] = *(const ushort8v*)&smem[so + 2048];
        *(ushort8v*)&hz_[8] = *(const ushort8v*)&smem[so + 2048 + 16];
        *(ushort8v*)&hn_[0] = *(const ushort8v*)&smem[so + 4096];
        *(ushort8v*)&hn_[8] = *(const ushort8v*)&smem[so + 4096 + 16];
#pragma unroll
        for (int r = 0; r < 16; ++r) {
          const int rowc = (r & 3) + 8 * (r >> 2) + 4 * lhi;
          const int grow = row0 + rt * 32 + rowc;
          if (grow < nn) {
            const float ir_ = acc[rt][0][r] + bir;
            const float iz_ = acc[rt][1][r] + biz;
            const float in_ = acc[rt][2][r] + bin;
            const float hr = bf2f(hr_[r]) + bhr;
            const float hz = bf2f(hz_[r]) + bhz;
            const float hn = bf2f(hn_[r]) + bhn;
            const float rg = 1.f / (1.f + __expf(-(ir_ + hr)));
            const float zg = 1.f / (1.f + __expf(-(iz_ + hz)));
            const float ng = tanhf(in_ + rg * hn);
            const float hv = bf2f(*(const ushort*)(hchar + hv_base + (rbase + rt * 32 + rowc) * 16));
            out[(size_t)grow * H + hcol] = (1.f - zg) * ng + zg * hv;
          }
        }
      }
    }
    __syncthreads();
  }
}

extern "C" void kernel_launch(void* const* d_in, const int* in_sizes, int n_in,
                              void* d_out, int out_size, void* d_ws, size_t ws_size,
                              hipStream_t stream) {
  const float* h    = (const float*)d_in[0];
  const float* relv = (const float*)d_in[1];
  const float* w_ih = (const float*)d_in[2];
  const float* w_hh = (const float*)d_in[3];
  const float* b_ih = (const float*)d_in[4];
  const float* b_hh = (const float*)d_in[5];
  const int* esrc   = (const int*)d_in[6];
  const int* edst   = (const int*)d_in[7];
  const int* erel   = (const int*)d_in[8];
  float* out = (float*)d_out;
  const int nn = in_sizes[0] / H;        // 50000
  const int ne = in_sizes[6];            // 800000
  const int npan = (nn + 127) / 128;     // 391
  const int nb = (nn + 255) / 256;       // 196

  // ---- workspace layout ----
  char* w = (char*)d_ws;
  ushort* redfm  = (ushort*)w;  w += (size_t)npan * 65536;       // 25.6 MB frag-major
  ushort* hfm    = (ushort*)w;  w += (size_t)npan * 65536;       // 25.6 MB frag-major
  ushort* h16row = (ushort*)w;  w += (size_t)nn * H * 2;         // 25.6 MB row-major
  ushort* wfm    = (ushort*)w;  w += (size_t)32 * 1536 * 16;     // 768 KB frag-major
  int* cnt16  = (int*)w;        w += (size_t)nn * 16 * 4;        // 3.2 MB
  int* offs   = (int*)w;        w += (size_t)(nn + 4) * 4;
  int* cursor = (int*)w;        w += (size_t)nn * 4;
  int* bsum   = (int*)w;        w += 256 * 4;
  int* bpre   = (int*)w;        w += 256 * 4;
  int* bucket = (int*)w;

  k_cvt_h<<<(nn * 32 + 255) / 256, 256, 0, stream>>>(h, h16row, hfm, nn);
  k_cvt_w<<<96, 256, 0, stream>>>(w_ih, wfm, 0);
  k_cvt_w<<<96, 256, 0, stream>>>(w_hh, wfm, 768);

  k_zero<<<(nn * 16 + 255) / 256, 256, 0, stream>>>(cnt16, nn * 16);
  k_hist<<<(ne + 255) / 256, 256, 0, stream>>>(edst, erel, cnt16, ne);
  k_scan1<<<nb, 256, 0, stream>>>(cnt16, bsum, nn);
  k_scan2<<<1, 256, 0, stream>>>(bsum, bpre, nb, offs, nn);
  k_scan3<<<nb, 256, 0, stream>>>(cnt16, bpre, offs, cursor, nn);
  k_fill<<<(ne + 255) / 256, 256, 0, stream>>>(esrc, edst, cursor, bucket, ne);

  k_gather<<<(nn + 7) / 8, 256, 0, stream>>>(h16row, relv, offs, bucket, cnt16, redfm, nn);

  k_gru_mfma<<<782, 256, 0, stream>>>(redfm, hfm, wfm, b_ih, b_hh, out, nn);
}

// Round 7
// 370.757 us; speedup vs baseline: 1.4251x; 1.4251x over previous
//
#include <hip/hip_runtime.h>

#define H 256

typedef __attribute__((ext_vector_type(8))) short short8;
typedef __attribute__((ext_vector_type(8))) unsigned short ushort8v;
typedef __attribute__((ext_vector_type(16))) float f32x16;

__device__ __forceinline__ ushort f2bf(float f) {
  unsigned u = __float_as_uint(f);
  unsigned r = (u + 0x7fffu + ((u >> 16) & 1u)) >> 16;
  return (ushort)r;
}
__device__ __forceinline__ float bf2f(ushort s) {
  return __uint_as_float(((unsigned)s) << 16);
}
__device__ __forceinline__ void gld_lds16(const void* g, void* lds) {
  __builtin_amdgcn_global_load_lds(
      (const __attribute__((address_space(1))) unsigned int*)g,
      (__attribute__((address_space(3))) unsigned int*)lds, 16, 0, 0);
}

// ============ frag-major layouts ============
// A-type (red, h): panel p = row>>7, r = row&127; chunk l = k>>3 (0..31).
//   byte addr = p*65536 + l*2048 + r*16   (panel = 64 KB)
// W (both mats, gidx = [ih: gate*256+col | hh: 768+gate*256+col]):
//   byte addr = l*24576 + gidx*16         (l = k>>3, 0..31; total 768 KB)

// ---------- h: f32 -> bf16 row-major (for gather) + frag-major (for GEMM) ----------
__global__ void k_cvt_h(const float* __restrict__ src, ushort* __restrict__ h16row,
                        ushort* __restrict__ hfm, int nrows) {
  int t = blockIdx.x * blockDim.x + threadIdx.x;
  if (t >= nrows * 32) return;
  const int row = t >> 5, l = t & 31;
  const float4 fa = *(const float4*)&src[(size_t)row * H + l * 8];
  const float4 fb = *(const float4*)&src[(size_t)row * H + l * 8 + 4];
  ushort8v o;
  o[0] = f2bf(fa.x); o[1] = f2bf(fa.y); o[2] = f2bf(fa.z); o[3] = f2bf(fa.w);
  o[4] = f2bf(fb.x); o[5] = f2bf(fb.y); o[6] = f2bf(fb.z); o[7] = f2bf(fb.w);
  *(ushort8v*)&h16row[(size_t)row * H + l * 8] = o;
  const int p = row >> 7, r = row & 127;
  *(ushort8v*)((char*)hfm + (size_t)p * 65536 + (size_t)l * 2048 + r * 16) = o;
}

// ---------- W: f32 -> bf16 frag-major ----------
__global__ void k_cvt_w(const float* __restrict__ w, ushort* __restrict__ wfm, int gbase) {
  int t = blockIdx.x * blockDim.x + threadIdx.x;
  if (t >= 768 * 32) return;
  const int j = t >> 5, l = t & 31;
  const float4 fa = *(const float4*)&w[(size_t)j * H + l * 8];
  const float4 fb = *(const float4*)&w[(size_t)j * H + l * 8 + 4];
  ushort8v o;
  o[0] = f2bf(fa.x); o[1] = f2bf(fa.y); o[2] = f2bf(fa.z); o[3] = f2bf(fa.w);
  o[4] = f2bf(fb.x); o[5] = f2bf(fb.y); o[6] = f2bf(fb.z); o[7] = f2bf(fb.w);
  *(ushort8v*)((char*)wfm + ((size_t)l * 1536 + gbase + j) * 16) = o;
}

// ---------- CSR build ----------
__global__ void k_zero(int* cnt, int n) {
  int i = blockIdx.x * blockDim.x + threadIdx.x;
  if (i < n) cnt[i] = 0;
}

// per-(dst,rel) histogram: cnt16[dst*16+rel]
__global__ void k_hist(const int* __restrict__ dst, const int* __restrict__ rel,
                       int* __restrict__ cnt16, int ne) {
  int e = blockIdx.x * blockDim.x + threadIdx.x;
  if (e < ne) atomicAdd(&cnt16[dst[e] * 16 + rel[e]], 1);
}

__device__ __forceinline__ int node_cnt(const int* __restrict__ cnt16, int i) {
  int s = 0;
#pragma unroll
  for (int r = 0; r < 16; ++r) s += cnt16[i * 16 + r];
  return s;
}

__global__ __launch_bounds__(256) void k_scan1(const int* __restrict__ cnt16,
                                               int* __restrict__ bsum, int n) {
  __shared__ int s[256];
  int t = threadIdx.x, i = blockIdx.x * 256 + t;
  int v = (i < n) ? node_cnt(cnt16, i) : 0;
  s[t] = v;
  __syncthreads();
  for (int o = 128; o > 0; o >>= 1) {
    if (t < o) s[t] += s[t + o];
    __syncthreads();
  }
  if (t == 0) bsum[blockIdx.x] = s[0];
}

__global__ __launch_bounds__(256) void k_scan2(const int* __restrict__ bsum,
                                               int* __restrict__ bpre, int nb,
                                               int* __restrict__ offs, int n) {
  __shared__ int s[256];
  int t = threadIdx.x;
  int v = (t < nb) ? bsum[t] : 0;
  s[t] = v;
  __syncthreads();
  for (int o = 1; o < 256; o <<= 1) {
    int x = (t >= o) ? s[t - o] : 0;
    __syncthreads();
    s[t] += x;
    __syncthreads();
  }
  if (t < nb) bpre[t] = s[t] - v;
  if (t == 255) offs[n] = s[255];
}

__global__ __launch_bounds__(256) void k_scan3(const int* __restrict__ cnt16,
                                               const int* __restrict__ bpre,
                                               int* __restrict__ offs,
                                               int* __restrict__ cursor, int n) {
  __shared__ int s[256];
  int t = threadIdx.x, i = blockIdx.x * 256 + t;
  int v = (i < n) ? node_cnt(cnt16, i) : 0;
  s[t] = v;
  __syncthreads();
  for (int o = 1; o < 256; o <<= 1) {
    int x = (t >= o) ? s[t - o] : 0;
    __syncthreads();
    s[t] += x;
    __syncthreads();
  }
  if (i < n) {
    int e = bpre[blockIdx.x] + s[t] - v;
    offs[i] = e;
    cursor[i] = e;
  }
}

__global__ void k_fill(const int* __restrict__ src, const int* __restrict__ dst,
                       int* __restrict__ cursor, int* __restrict__ bucket, int ne) {
  int e = blockIdx.x * blockDim.x + threadIdx.x;
  if (e < ne) {
    int p = atomicAdd(&cursor[dst[e]], 1);
    bucket[p] = src[e];
  }
}

// ---------- gather-reduce: half-wave per node; edge loop = h only; relv via counts ----------
__global__ __launch_bounds__(256) void k_gather(const ushort* __restrict__ h16,
                                                const float* __restrict__ relv,
                                                const int* __restrict__ offs,
                                                const int* __restrict__ bucket,
                                                const int* __restrict__ cnt16,
                                                ushort* __restrict__ redfm, int nn) {
  const int hw = threadIdx.x >> 5;
  const int l = threadIdx.x & 31;
  const int node = blockIdx.x * 8 + hw;
  if (node >= nn) return;
  const int beg = offs[node], end = offs[node + 1];
  float acc[8] = {0.f, 0.f, 0.f, 0.f, 0.f, 0.f, 0.f, 0.f};
  int i = beg;
  for (; i + 4 <= end; i += 4) {
    const int s0 = bucket[i], s1 = bucket[i + 1], s2 = bucket[i + 2], s3 = bucket[i + 3];
    const ushort8v a0 = *(const ushort8v*)&h16[(size_t)s0 * H + l * 8];
    const ushort8v a1 = *(const ushort8v*)&h16[(size_t)s1 * H + l * 8];
    const ushort8v a2 = *(const ushort8v*)&h16[(size_t)s2 * H + l * 8];
    const ushort8v a3 = *(const ushort8v*)&h16[(size_t)s3 * H + l * 8];
#pragma unroll
    for (int e = 0; e < 8; ++e)
      acc[e] += (bf2f(a0[e]) + bf2f(a1[e])) + (bf2f(a2[e]) + bf2f(a3[e]));
  }
  for (; i < end; ++i) {
    const int s0 = bucket[i];
    const ushort8v a0 = *(const ushort8v*)&h16[(size_t)s0 * H + l * 8];
#pragma unroll
    for (int e = 0; e < 8; ++e) acc[e] += bf2f(a0[e]);
  }
#pragma unroll 4
  for (int r = 0; r < 16; ++r) {
    const float cf = (float)cnt16[node * 16 + r];
    const float4 ra = *(const float4*)&relv[r * H + l * 8];
    const float4 rb = *(const float4*)&relv[r * H + l * 8 + 4];
    acc[0] += cf * ra.x; acc[1] += cf * ra.y; acc[2] += cf * ra.z; acc[3] += cf * ra.w;
    acc[4] += cf * rb.x; acc[5] += cf * rb.y; acc[6] += cf * rb.z; acc[7] += cf * rb.w;
  }
  ushort8v o;
#pragma unroll
  for (int e = 0; e < 8; ++e) o[e] = f2bf(acc[e]);
  const int p = node >> 7, r = node & 127;
  *(ushort8v*)((char*)redfm + (size_t)p * 65536 + (size_t)l * 2048 + r * 16) = o;
}

// ---------- fused dual-GEMM (32x32x16 bf16 MFMA, LDS double-buffered) + GRU ----------
// Grid (391, 4): block = 512 thr (8 waves), 128 rows x 64 h-cols.
// LDS buffer (40 KB, x2 dbuf = 80 KB): per kb (BK=32, 4 frag-lines):
//   A_red [4 line][128 r][16B] @0 (8K) | A_h @8192 | W [4 line][6 strip][64 c][16B] @16384 (24K)
// Staging: 40 x gld_lds16, each = 1 KB CONTIGUOUS global src (frag-major) -> 1 request.
// Waves: wid<4 ih / wid>=4 hh; R0=((wid>>1)&1)*64, C=(wid&1)*32; acc 2x3 tiles (96 AGPR).
// Budget: launch_bounds(512,2) -> 256 regs/wave, no spill (round-6 lesson).
__global__ __launch_bounds__(512, 2) void k_gru_mfma(
    const ushort* __restrict__ redfm, const ushort* __restrict__ hfm,
    const ushort* __restrict__ wfm,
    const float* __restrict__ b_ih, const float* __restrict__ b_hh,
    float* __restrict__ out, int nn) {
  __shared__ unsigned char smem[81920];
  const int tid = threadIdx.x;
  const int wid = tid >> 6;
  const int lane = tid & 63;
  const int l31 = lane & 31;
  const int lhi = lane >> 5;
  const bool is_hh = (wid >= 4);
  const int R0 = ((wid >> 1) & 1) * 64;
  const int C = (wid & 1) * 32;
  const int p = blockIdx.x;
  const int row0 = p * 128;
  const int hcol0 = blockIdx.y * 64;

  const char* redc = (const char*)redfm;
  const char* hc = (const char*)hfm;
  const char* wc = (const char*)wfm;

  // staging constants: wave stages items {wid, wid+8, wid+16, wid+24, wid+32}
  const int aline = wid >> 1, ahalf = wid & 1;           // items 0-7: A_red, 8-15: A_h
  const size_t a_src = (size_t)p * 65536 + (size_t)ahalf * 1024 + (size_t)lane * 16;
  const int a_dst = aline * 2048 + ahalf * 1024;
  size_t w_src[3];
  int w_ln[3], w_dst[3];
#pragma unroll
  for (int j = 0; j < 3; ++j) {                          // items 16-39: W, q = wid+8j
    const int q = wid + 8 * j;
    const int ln = q / 6, s = q % 6;
    const int gb = (s < 3) ? s * 256 : 768 + (s - 3) * 256;
    w_ln[j] = ln;
    w_src[j] = (size_t)(gb + hcol0) * 16 + (size_t)lane * 16;
    w_dst[j] = 16384 + ln * 6144 + s * 1024;
  }

#define STAGE(bufo, kb) do { \
    const size_t ko_ = (size_t)(kb) * 4; \
    gld_lds16(redc + a_src + (ko_ + aline) * 2048, &smem[(bufo) + a_dst]); \
    gld_lds16(hc + a_src + (ko_ + aline) * 2048, &smem[(bufo) + 8192 + a_dst]); \
    gld_lds16(wc + w_src[0] + (ko_ + w_ln[0]) * 24576, &smem[(bufo) + w_dst[0]]); \
    gld_lds16(wc + w_src[1] + (ko_ + w_ln[1]) * 24576, &smem[(bufo) + w_dst[1]]); \
    gld_lds16(wc + w_src[2] + (ko_ + w_ln[2]) * 24576, &smem[(bufo) + w_dst[2]]); \
  } while (0)

  f32x16 acc[2][3] = {};
  const int sgb = is_hh ? 3 : 0;

  STAGE(0, 0);
  __syncthreads();
  for (int kb = 0; kb < 8; ++kb) {
    const int bo = (kb & 1) * 40960;
    if (kb < 7) STAGE(40960 - bo, kb + 1);
    const int abase = bo + (is_hh ? 8192 : 0);
#pragma unroll
    for (int kg = 0; kg < 2; ++kg) {
      const int ko = kg * 2 + lhi;
      const short8 a0 = *(const short8*)&smem[abase + ko * 2048 + (R0 + l31) * 16];
      const short8 a1 = *(const short8*)&smem[abase + ko * 2048 + (R0 + 32 + l31) * 16];
      const short8 b0 = *(const short8*)&smem[bo + 16384 + ko * 6144 + (sgb + 0) * 1024 + (C + l31) * 16];
      const short8 b1 = *(const short8*)&smem[bo + 16384 + ko * 6144 + (sgb + 1) * 1024 + (C + l31) * 16];
      const short8 b2 = *(const short8*)&smem[bo + 16384 + ko * 6144 + (sgb + 2) * 1024 + (C + l31) * 16];
      acc[0][0] = __builtin_amdgcn_mfma_f32_32x32x16_bf16(a0, b0, acc[0][0], 0, 0, 0);
      acc[0][1] = __builtin_amdgcn_mfma_f32_32x32x16_bf16(a0, b1, acc[0][1], 0, 0, 0);
      acc[0][2] = __builtin_amdgcn_mfma_f32_32x32x16_bf16(a0, b2, acc[0][2], 0, 0, 0);
      acc[1][0] = __builtin_amdgcn_mfma_f32_32x32x16_bf16(a1, b0, acc[1][0], 0, 0, 0);
      acc[1][1] = __builtin_amdgcn_mfma_f32_32x32x16_bf16(a1, b1, acc[1][1], 0, 0, 0);
      acc[1][2] = __builtin_amdgcn_mfma_f32_32x32x16_bf16(a1, b2, acc[1][2], 0, 0, 0);
    }
    __syncthreads();
  }
#undef STAGE

  // --- exchange: hh waves stash gh (bf16) into LDS (reuses buffers) ---
  if (is_hh) {
    const int ww = wid - 4;
#pragma unroll
    for (int rt = 0; rt < 2; ++rt)
#pragma unroll
      for (int s = 0; s < 3; ++s) {
        ushort tmp[16];
#pragma unroll
        for (int r = 0; r < 16; ++r) tmp[r] = f2bf(acc[rt][s][r]);
        const int so = ww * 12288 + (rt * 3 + s) * 2048 + lane * 32;
        *(ushort8v*)&smem[so] = *(const ushort8v*)&tmp[0];
        *(ushort8v*)&smem[so + 16] = *(const ushort8v*)&tmp[8];
      }
  }
  __syncthreads();

  // --- ih waves: fused GRU epilogue (hv from bf16 hfm) ---
  if (!is_hh) {
    const int hcol = hcol0 + C + l31;
    const float bir = b_ih[hcol], biz = b_ih[256 + hcol], bin = b_ih[512 + hcol];
    const float bhr = b_hh[hcol], bhz = b_hh[256 + hcol], bhn = b_hh[512 + hcol];
    const size_t hv_base = (size_t)p * 65536 + (size_t)(hcol >> 3) * 2048 + (hcol & 7) * 2;
#pragma unroll
    for (int rt = 0; rt < 2; ++rt) {
      ushort hr_[16], hz_[16], hn_[16];
      const int so = wid * 12288 + rt * 3 * 2048 + lane * 32;
      *(ushort8v*)&hr_[0] = *(const ushort8v*)&smem[so];
      *(ushort8v*)&hr_[8] = *(const ushort8v*)&smem[so + 16];
      *(ushort8v*)&hz_[0] = *(const ushort8v*)&smem[so + 2048];
      *(ushort8v*)&hz_[8] = *(const ushort8v*)&smem[so + 2048 + 16];
      *(ushort8v*)&hn_[0] = *(const ushort8v*)&smem[so + 4096];
      *(ushort8v*)&hn_[8] = *(const ushort8v*)&smem[so + 4096 + 16];
#pragma unroll
      for (int r = 0; r < 16; ++r) {
        const int rowc = (r & 3) + 8 * (r >> 2) + 4 * lhi;
        const int rloc = R0 + rt * 32 + rowc;
        const int grow = row0 + rloc;
        if (grow < nn) {
          const float ir_ = acc[rt][0][r] + bir;
          const float iz_ = acc[rt][1][r] + biz;
          const float in_ = acc[rt][2][r] + bin;
          const float hr = bf2f(hr_[r]) + bhr;
          const float hz = bf2f(hz_[r]) + bhz;
          const float hn = bf2f(hn_[r]) + bhn;
          const float rg = 1.f / (1.f + __expf(-(ir_ + hr)));
          const float zg = 1.f / (1.f + __expf(-(iz_ + hz)));
          const float ng = tanhf(in_ + rg * hn);
          const float hv = bf2f(*(const ushort*)(hc + hv_base + (size_t)rloc * 16));
          out[(size_t)grow * H + hcol] = (1.f - zg) * ng + zg * hv;
        }
      }
    }
  }
}

extern "C" void kernel_launch(void* const* d_in, const int* in_sizes, int n_in,
                              void* d_out, int out_size, void* d_ws, size_t ws_size,
                              hipStream_t stream) {
  const float* h    = (const float*)d_in[0];
  const float* relv = (const float*)d_in[1];
  const float* w_ih = (const float*)d_in[2];
  const float* w_hh = (const float*)d_in[3];
  const float* b_ih = (const float*)d_in[4];
  const float* b_hh = (const float*)d_in[5];
  const int* esrc   = (const int*)d_in[6];
  const int* edst   = (const int*)d_in[7];
  const int* erel   = (const int*)d_in[8];
  float* out = (float*)d_out;
  const int nn = in_sizes[0] / H;        // 50000
  const int ne = in_sizes[6];            // 800000
  const int npan = (nn + 127) / 128;     // 391
  const int nb = (nn + 255) / 256;       // 196

  // ---- workspace layout ----
  char* w = (char*)d_ws;
  ushort* redfm  = (ushort*)w;  w += (size_t)npan * 65536;       // 25.6 MB frag-major
  ushort* hfm    = (ushort*)w;  w += (size_t)npan * 65536;       // 25.6 MB frag-major
  ushort* h16row = (ushort*)w;  w += (size_t)nn * H * 2;         // 25.6 MB row-major
  ushort* wfm    = (ushort*)w;  w += (size_t)32 * 1536 * 16;     // 768 KB frag-major
  int* cnt16  = (int*)w;        w += (size_t)nn * 16 * 4;        // 3.2 MB
  int* offs   = (int*)w;        w += (size_t)(nn + 4) * 4;
  int* cursor = (int*)w;        w += (size_t)nn * 4;
  int* bsum   = (int*)w;        w += 256 * 4;
  int* bpre   = (int*)w;        w += 256 * 4;
  int* bucket = (int*)w;

  k_cvt_h<<<(nn * 32 + 255) / 256, 256, 0, stream>>>(h, h16row, hfm, nn);
  k_cvt_w<<<96, 256, 0, stream>>>(w_ih, wfm, 0);
  k_cvt_w<<<96, 256, 0, stream>>>(w_hh, wfm, 768);

  k_zero<<<(nn * 16 + 255) / 256, 256, 0, stream>>>(cnt16, nn * 16);
  k_hist<<<(ne + 255) / 256, 256, 0, stream>>>(edst, erel, cnt16, ne);
  k_scan1<<<nb, 256, 0, stream>>>(cnt16, bsum, nn);
  k_scan2<<<1, 256, 0, stream>>>(bsum, bpre, nb, offs, nn);
  k_scan3<<<nb, 256, 0, stream>>>(cnt16, bpre, offs, cursor, nn);
  k_fill<<<(ne + 255) / 256, 256, 0, stream>>>(esrc, edst, cursor, bucket, ne);

  k_gather<<<(nn + 7) / 8, 256, 0, stream>>>(h16row, relv, offs, bucket, cnt16, redfm, nn);

  dim3 grid((nn + 127) / 128, 4);
  k_gru_mfma<<<grid, 512, 0, stream>>>(redfm, hfm, wfm, b_ih, b_hh, out, nn);
}